// Round 1
// baseline (691.414 us; speedup 1.0000x reference)
//
#include <hip/hip_runtime.h>
#include <math.h>

// Problem constants
#define HW 65536          // 256*256
#define NPAD 258          // padded spatial dim

typedef short bf16x8 __attribute__((ext_vector_type(8)));
typedef float f32x4  __attribute__((ext_vector_type(4)));

// Workspace layout (bytes)
#define O_COUNTS 0            // 12 ints
#define O_W2C    256          // 8 * 16 floats = 512 B
#define O_WT     1024         // 2 convs * 36864 bf16 = 147456 B  [cv][h][tap][q][co][8ci]
#define O_META   148480       // 12 * 65536 ints = 3 MiB
#define O_FUSED  3294208      // 8*258*258*64 bf16 = 68,161,536 B
#define O_X1     71455744     // same size
// total = 139,617,280 B

__device__ __forceinline__ unsigned short f2bf(float f) {
    unsigned int u = __float_as_uint(f);
    u += 0x7FFFu + ((u >> 16) & 1u);   // round-to-nearest-even
    return (unsigned short)(u >> 16);
}

// ---------------------------------------------------------------------------
// Prep: invert extrinsics (exact for [[I,t],[0,1]]), build bf16 weight
// fragment image [h][tap][q][co][8ci], zero padded-buffer borders, zero counts
// ---------------------------------------------------------------------------
__global__ __launch_bounds__(256) void prep_kernel(
    const float* __restrict__ extr, const float* __restrict__ w1,
    const float* __restrict__ w2, float* __restrict__ w2c,
    unsigned short* __restrict__ wT, unsigned short* __restrict__ fusedP,
    unsigned short* __restrict__ x1P, int* __restrict__ counts)
{
    int tid = blockIdx.x * blockDim.x + threadIdx.x;
    int nth = gridDim.x * blockDim.x;

    if (blockIdx.x == 0) {
        if (threadIdx.x < 8) {
            // Gauss-Jordan 4x4 inverse with partial pivoting (exact here)
            float a[4][8];
            const float* E = extr + threadIdx.x * 16;
            for (int r = 0; r < 4; r++)
                for (int c = 0; c < 4; c++) {
                    a[r][c] = E[r*4 + c];
                    a[r][4+c] = (r == c) ? 1.0f : 0.0f;
                }
            for (int col = 0; col < 4; col++) {
                int piv = col; float bm = fabsf(a[col][col]);
                for (int r = col+1; r < 4; r++) {
                    float v = fabsf(a[r][col]);
                    if (v > bm) { bm = v; piv = r; }
                }
                if (piv != col)
                    for (int c = 0; c < 8; c++) { float t = a[col][c]; a[col][c] = a[piv][c]; a[piv][c] = t; }
                float f = 1.0f / a[col][col];
                for (int c = 0; c < 8; c++) a[col][c] *= f;
                for (int r = 0; r < 4; r++) if (r != col) {
                    float f2 = a[r][col];
                    for (int c = 0; c < 8; c++) a[r][c] -= f2 * a[col][c];
                }
            }
            float* O = w2c + threadIdx.x * 16;
            for (int r = 0; r < 4; r++)
                for (int c = 0; c < 4; c++) O[r*4+c] = a[r][4+c];
        }
        if (threadIdx.x >= 32 && threadIdx.x < 44) counts[threadIdx.x - 32] = 0;
    }

    // Weight fragment image: 2 convs * [h2][tap9][q4][co64][j8]
    for (int e = tid; e < 73728; e += nth) {
        int t = e;
        int j  = t & 7;  t >>= 3;
        int co = t & 63; t >>= 6;
        int q  = t & 3;  t >>= 2;
        int tap = t % 9; t /= 9;
        int h  = t & 1;  int cv = t >> 1;
        int ci = h*32 + q*8 + j;
        int ky = tap / 3, kx = tap % 3;
        const float* wsrc = cv ? w2 : w1;
        float v = wsrc[((co*64 + ci)*3 + ky)*3 + kx];
        wT[cv*36864 + ((((h*9 + tap)*4 + q)*64 + co)*8 + j)] = f2bf(v);
    }

    // Zero borders of both padded buffers (1028 border cells per image, 8 ch-chunks)
    for (int u = tid; u < 2*8*1028*8; u += nth) {
        int t = u;
        int ch   = t & 7;    t >>= 3;
        int cell = t % 1028; t /= 1028;
        int n    = t & 7;    int buf = t >> 3;
        int y, x;
        if      (cell < 258) { y = 0;   x = cell; }
        else if (cell < 516) { y = 257; x = cell - 258; }
        else if (cell < 772) { y = cell - 516 + 1; x = 0; }
        else                 { y = cell - 772 + 1; x = 257; }
        unsigned short* p = (buf ? x1P : fusedP) +
            (((size_t)(n*NPAD + y)*NPAD + x)*64 + ch*8);
        *reinterpret_cast<uint4*>(p) = make_uint4(0u, 0u, 0u, 0u);
    }
}

// ---------------------------------------------------------------------------
// Projection: per (b, j->k) pair, compute mask|idx per point + valid counts
// ---------------------------------------------------------------------------
__global__ __launch_bounds__(256) void proj_kernel(
    const float* __restrict__ means, const float* __restrict__ intr,
    const float* __restrict__ w2c, int* __restrict__ meta,
    int* __restrict__ counts)
{
    const int jt[6] = {0,1,1,2,2,3};
    const int kt[6] = {1,0,2,1,3,2};
    int s = blockIdx.y;            // 0..11
    int b = s / 6, p = s % 6;
    int j = jt[p], k = kt[p];
    int i = blockIdx.x * 256 + threadIdx.x;

    const float* mp = means + ((size_t)(b*4 + j)*HW + i)*3;
    float x = mp[0], y = mp[1], z = mp[2];
    const float* M = w2c + (b*4 + k)*16;
    const float* I = intr + (b*4 + k)*9;

    float cx = fmaf(M[2],  z, fmaf(M[1], y, M[0]*x)) + M[3];
    float cy = fmaf(M[6],  z, fmaf(M[5], y, M[4]*x)) + M[7];
    float cz = fmaf(M[10], z, fmaf(M[9], y, M[8]*x)) + M[11];

    bool vz = cz > 1e-8f;
    float zi = cz + 1e-8f;
    float sx = cx / zi, sy = cy / zi, sz = cz / zi;
    float nx = fmaf(I[2], sz, fmaf(I[1], sy, I[0]*sx));
    float ny = fmaf(I[5], sz, fmaf(I[4], sy, I[3]*sx));

    int px = (int)floorf(nx * 256.0f);
    int py = (int)floorf(ny * 256.0f);
    bool mask = (nx >= 0.0f) && (nx < 1.0f) && (ny >= 0.0f) && (ny < 1.0f) && vz;
    int pxc = min(max(px, 0), 255);
    int pyc = min(max(py, 0), 255);
    int idx = pyc*256 + pxc;
    meta[(size_t)s*HW + i] = idx | (mask ? (int)0x80000000 : 0);

    unsigned long long bal = __ballot(mask ? 1 : 0);
    if ((threadIdx.x & 63) == 0)
        atomicAdd(counts + s, (int)__popcll(bal));
}

// ---------------------------------------------------------------------------
// Fusion: acc = feats_j + sum_k scale_k * masked_gather(feats_k); /norm; bf16
// Thread layout: 16 points x 16 channel-quads per block (coalesced)
// ---------------------------------------------------------------------------
__global__ __launch_bounds__(256) void fuse_kernel(
    const float* __restrict__ feats, const int* __restrict__ meta,
    const int* __restrict__ counts, unsigned short* __restrict__ fusedP)
{
    const int nsl[4]    = {1, 2, 2, 1};
    const int slt[4][2] = {{0,0},{1,2},{3,4},{5,5}};
    const int kvw[4][2] = {{1,1},{0,2},{1,3},{2,2}};

    int bj = blockIdx.y;           // n = b*4 + j
    int b = bj >> 2, j = bj & 3;
    int pt = blockIdx.x * 16 + (threadIdx.x >> 4);
    int cg = threadIdx.x & 15;

    const float4* fj = reinterpret_cast<const float4*>(
        feats + ((size_t)bj*HW + pt)*64) + cg;
    float4 acc = *fj;
    float norm = 1.0f;
    int ns = nsl[j];
    for (int e = 0; e < 2; e++) {
        if (e < ns) {
            int p = slt[j][e], k = kvw[j][e];
            int s = b*6 + p;
            float scale = 0.1f * (float)counts[s] / 65536.0f;
            int mt = meta[(size_t)s*HW + pt];
            if (mt < 0) {
                int idx = mt & 0xFFFF;
                const float4* g = reinterpret_cast<const float4*>(
                    feats + ((size_t)(b*4 + k)*HW + idx)*64) + cg;
                float4 gv = *g;
                acc.x += scale * gv.x; acc.y += scale * gv.y;
                acc.z += scale * gv.z; acc.w += scale * gv.w;
            }
            norm += scale;
        }
    }
    float ox = acc.x / norm, oy = acc.y / norm;
    float oz = acc.z / norm, ow = acc.w / norm;

    int yy = pt >> 8, xx = pt & 255;
    unsigned short* op = fusedP +
        (((size_t)bj*NPAD + (yy+1))*NPAD + (xx+1))*64 + cg*4;
    ushort4 o = make_ushort4(f2bf(ox), f2bf(oy), f2bf(oz), f2bf(ow));
    *reinterpret_cast<ushort4*>(op) = o;
}

// ---------------------------------------------------------------------------
// 3x3 conv as 18 shifted K=32 MFMA steps. Block = 128 thr (2 waves), each
// wave owns 64 px x 64 co. A-frags from padded NHWC bf16 global (L1/L2),
// B-frags from fragment-native weight image. MODE 1: +bias,GELU,bf16-padded;
// MODE 2: +bias, fp32 to d_out.
// ---------------------------------------------------------------------------
template<int MODE>
__global__ __launch_bounds__(128) void conv_kernel(
    const unsigned short* __restrict__ in, const unsigned short* __restrict__ wT,
    const float* __restrict__ bias, void* __restrict__ outp)
{
    int n = blockIdx.z, y = blockIdx.y;
    int wv = threadIdx.x >> 6;
    int lane = threadIdx.x & 63;
    int m = lane & 15, q = lane >> 4;
    int x0 = blockIdx.x * 128 + wv * 64;

    f32x4 acc[4][4];
#pragma unroll
    for (int a = 0; a < 4; a++)
#pragma unroll
        for (int bq = 0; bq < 4; bq++)
            acc[a][bq] = (f32x4){0.f, 0.f, 0.f, 0.f};

#pragma unroll
    for (int h = 0; h < 2; h++) {
#pragma unroll
        for (int tap = 0; tap < 9; tap++) {
            int dy = tap/3 - 1, dx = tap%3 - 1;
            const unsigned short* rp = in +
                ((size_t)(n*NPAD + (y + dy + 1))*NPAD)*64 + h*32 + q*8;
            bf16x8 av[4], bv[4];
#pragma unroll
            for (int Mt = 0; Mt < 4; Mt++)
                av[Mt] = *reinterpret_cast<const bf16x8*>(
                    rp + (size_t)(x0 + Mt*16 + m + dx + 1)*64);
            const unsigned short* wp = wT + (size_t)(((h*9 + tap)*4 + q)*64)*8;
#pragma unroll
            for (int Nt = 0; Nt < 4; Nt++)
                bv[Nt] = *reinterpret_cast<const bf16x8*>(wp + (Nt*16 + m)*8);
#pragma unroll
            for (int Mt = 0; Mt < 4; Mt++)
#pragma unroll
                for (int Nt = 0; Nt < 4; Nt++)
                    acc[Mt][Nt] = __builtin_amdgcn_mfma_f32_16x16x32_bf16(
                        av[Mt], bv[Nt], acc[Mt][Nt], 0, 0, 0);
        }
    }

    // Epilogue. C/D: col(co) = lane&15, row(px) = (lane>>4)*4 + r
#pragma unroll
    for (int Nt = 0; Nt < 4; Nt++) {
        int co = Nt*16 + m;
        float bs = bias[co];
#pragma unroll
        for (int Mt = 0; Mt < 4; Mt++) {
#pragma unroll
            for (int r = 0; r < 4; r++) {
                float v = acc[Mt][Nt][r] + bs;
                int px = x0 + Mt*16 + q*4 + r;
                if (MODE == 1) {
                    v = 0.5f * v * (1.0f + erff(v * 0.70710678118654752f));
                    unsigned short* o = (unsigned short*)outp +
                        ((size_t)(n*NPAD + y + 1)*NPAD + (px + 1))*64 + co;
                    *o = f2bf(v);
                } else {
                    float* o = (float*)outp +
                        ((size_t)(n*256 + y)*256 + px)*64 + co;
                    *o = v;
                }
            }
        }
    }
}

extern "C" void kernel_launch(void* const* d_in, const int* in_sizes, int n_in,
                              void* d_out, int out_size, void* d_ws, size_t ws_size,
                              hipStream_t stream)
{
    const float* means = (const float*)d_in[0];
    // d_in[1] = depths (unused by reference math)
    const float* feats = (const float*)d_in[2];
    const float* intr  = (const float*)d_in[3];
    const float* extr  = (const float*)d_in[4];
    const float* w1    = (const float*)d_in[5];
    const float* b1    = (const float*)d_in[6];
    const float* w2    = (const float*)d_in[7];
    const float* b2    = (const float*)d_in[8];

    char* ws = (char*)d_ws;
    int*            counts = (int*)(ws + O_COUNTS);
    float*          w2c    = (float*)(ws + O_W2C);
    unsigned short* wT     = (unsigned short*)(ws + O_WT);
    int*            meta   = (int*)(ws + O_META);
    unsigned short* fusedP = (unsigned short*)(ws + O_FUSED);
    unsigned short* x1P    = (unsigned short*)(ws + O_X1);

    prep_kernel<<<dim3(96), dim3(256), 0, stream>>>(
        extr, w1, w2, w2c, wT, fusedP, x1P, counts);
    proj_kernel<<<dim3(256, 12), dim3(256), 0, stream>>>(
        means, intr, w2c, meta, counts);
    fuse_kernel<<<dim3(4096, 8), dim3(256), 0, stream>>>(
        feats, meta, counts, fusedP);
    conv_kernel<1><<<dim3(2, 256, 8), dim3(128), 0, stream>>>(
        fusedP, wT, b1, (void*)x1P);
    conv_kernel<2><<<dim3(2, 256, 8), dim3(128), 0, stream>>>(
        x1P, wT + 36864, b2, d_out);
}

// Round 2
// 557.570 us; speedup vs baseline: 1.2400x; 1.2400x over previous
//
#include <hip/hip_runtime.h>
#include <math.h>

// Problem constants
#define HW 65536          // 256*256
#define NPAD 258          // padded spatial dim

typedef short bf16x8 __attribute__((ext_vector_type(8)));
typedef float f32x4  __attribute__((ext_vector_type(4)));

// Workspace layout (bytes)
#define O_COUNTS 0            // 12 ints
#define O_W2C    256          // 8 * 16 floats = 512 B
#define O_WT     1024         // 2 convs * 36864 bf16 = 147456 B  [cv][h][tap][q][co][8ci]
#define O_META   148480       // 12 * 65536 ints = 3 MiB
#define O_FUSED  3294208      // 8*258*258*64 bf16 = 68,161,536 B
#define O_X1     71455744     // same size
// total = 139,617,280 B

// Conv LDS tile: 6 padded rows x 66 px x 64ch bf16
#define ROWPX 66
#define ROWB  (ROWPX * 128)       // 8448 B per row
#define ROWSTR (ROWB + 16)        // +16 B pad between rows
#define ROWSTRS (ROWSTR / 2)      // stride in shorts (4232)

__device__ __forceinline__ unsigned short f2bf(float f) {
    unsigned int u = __float_as_uint(f);
    u += 0x7FFFu + ((u >> 16) & 1u);   // round-to-nearest-even
    return (unsigned short)(u >> 16);
}

// ---------------------------------------------------------------------------
// Prep: invert extrinsics, build bf16 weight fragment image [h][tap][q][co][8ci],
// zero padded-buffer borders, zero counts
// ---------------------------------------------------------------------------
__global__ __launch_bounds__(256) void prep_kernel(
    const float* __restrict__ extr, const float* __restrict__ w1,
    const float* __restrict__ w2, float* __restrict__ w2c,
    unsigned short* __restrict__ wT, unsigned short* __restrict__ fusedP,
    unsigned short* __restrict__ x1P, int* __restrict__ counts)
{
    int tid = blockIdx.x * blockDim.x + threadIdx.x;
    int nth = gridDim.x * blockDim.x;

    if (blockIdx.x == 0) {
        if (threadIdx.x < 8) {
            float a[4][8];
            const float* E = extr + threadIdx.x * 16;
            for (int r = 0; r < 4; r++)
                for (int c = 0; c < 4; c++) {
                    a[r][c] = E[r*4 + c];
                    a[r][4+c] = (r == c) ? 1.0f : 0.0f;
                }
            for (int col = 0; col < 4; col++) {
                int piv = col; float bm = fabsf(a[col][col]);
                for (int r = col+1; r < 4; r++) {
                    float v = fabsf(a[r][col]);
                    if (v > bm) { bm = v; piv = r; }
                }
                if (piv != col)
                    for (int c = 0; c < 8; c++) { float t = a[col][c]; a[col][c] = a[piv][c]; a[piv][c] = t; }
                float f = 1.0f / a[col][col];
                for (int c = 0; c < 8; c++) a[col][c] *= f;
                for (int r = 0; r < 4; r++) if (r != col) {
                    float f2 = a[r][col];
                    for (int c = 0; c < 8; c++) a[r][c] -= f2 * a[col][c];
                }
            }
            float* O = w2c + threadIdx.x * 16;
            for (int r = 0; r < 4; r++)
                for (int c = 0; c < 4; c++) O[r*4+c] = a[r][4+c];
        }
        if (threadIdx.x >= 32 && threadIdx.x < 44) counts[threadIdx.x - 32] = 0;
    }

    // Weight fragment image: 2 convs * [h2][tap9][q4][co64][j8]
    for (int e = tid; e < 73728; e += nth) {
        int t = e;
        int j  = t & 7;  t >>= 3;
        int co = t & 63; t >>= 6;
        int q  = t & 3;  t >>= 2;
        int tap = t % 9; t /= 9;
        int h  = t & 1;  int cv = t >> 1;
        int ci = h*32 + q*8 + j;
        int ky = tap / 3, kx = tap % 3;
        const float* wsrc = cv ? w2 : w1;
        float v = wsrc[((co*64 + ci)*3 + ky)*3 + kx];
        wT[cv*36864 + ((((h*9 + tap)*4 + q)*64 + co)*8 + j)] = f2bf(v);
    }

    // Zero borders of both padded buffers
    for (int u = tid; u < 2*8*1028*8; u += nth) {
        int t = u;
        int ch   = t & 7;    t >>= 3;
        int cell = t % 1028; t /= 1028;
        int n    = t & 7;    int buf = t >> 3;
        int y, x;
        if      (cell < 258) { y = 0;   x = cell; }
        else if (cell < 516) { y = 257; x = cell - 258; }
        else if (cell < 772) { y = cell - 516 + 1; x = 0; }
        else                 { y = cell - 772 + 1; x = 257; }
        unsigned short* p = (buf ? x1P : fusedP) +
            (((size_t)(n*NPAD + y)*NPAD + x)*64 + ch*8);
        *reinterpret_cast<uint4*>(p) = make_uint4(0u, 0u, 0u, 0u);
    }
}

// ---------------------------------------------------------------------------
// Projection: per (b, j->k) pair, compute mask|idx per point + valid counts
// ---------------------------------------------------------------------------
__global__ __launch_bounds__(256) void proj_kernel(
    const float* __restrict__ means, const float* __restrict__ intr,
    const float* __restrict__ w2c, int* __restrict__ meta,
    int* __restrict__ counts)
{
    const int jt[6] = {0,1,1,2,2,3};
    const int kt[6] = {1,0,2,1,3,2};
    int s = blockIdx.y;            // 0..11
    int b = s / 6, p = s % 6;
    int j = jt[p], k = kt[p];
    int i = blockIdx.x * 256 + threadIdx.x;

    const float* mp = means + ((size_t)(b*4 + j)*HW + i)*3;
    float x = mp[0], y = mp[1], z = mp[2];
    const float* M = w2c + (b*4 + k)*16;
    const float* I = intr + (b*4 + k)*9;

    float cx = fmaf(M[2],  z, fmaf(M[1], y, M[0]*x)) + M[3];
    float cy = fmaf(M[6],  z, fmaf(M[5], y, M[4]*x)) + M[7];
    float cz = fmaf(M[10], z, fmaf(M[9], y, M[8]*x)) + M[11];

    bool vz = cz > 1e-8f;
    float zi = cz + 1e-8f;
    float sx = cx / zi, sy = cy / zi, sz = cz / zi;
    float nx = fmaf(I[2], sz, fmaf(I[1], sy, I[0]*sx));
    float ny = fmaf(I[5], sz, fmaf(I[4], sy, I[3]*sx));

    int px = (int)floorf(nx * 256.0f);
    int py = (int)floorf(ny * 256.0f);
    bool mask = (nx >= 0.0f) && (nx < 1.0f) && (ny >= 0.0f) && (ny < 1.0f) && vz;
    int pxc = min(max(px, 0), 255);
    int pyc = min(max(py, 0), 255);
    int idx = pyc*256 + pxc;
    meta[(size_t)s*HW + i] = idx | (mask ? (int)0x80000000 : 0);

    unsigned long long bal = __ballot(mask ? 1 : 0);
    if ((threadIdx.x & 63) == 0)
        atomicAdd(counts + s, (int)__popcll(bal));
}

// ---------------------------------------------------------------------------
// Fusion: acc = feats_j + sum_k scale_k * masked_gather(feats_k); /norm; bf16
// ---------------------------------------------------------------------------
__global__ __launch_bounds__(256) void fuse_kernel(
    const float* __restrict__ feats, const int* __restrict__ meta,
    const int* __restrict__ counts, unsigned short* __restrict__ fusedP)
{
    const int nsl[4]    = {1, 2, 2, 1};
    const int slt[4][2] = {{0,0},{1,2},{3,4},{5,5}};
    const int kvw[4][2] = {{1,1},{0,2},{1,3},{2,2}};

    int bj = blockIdx.y;           // n = b*4 + j
    int b = bj >> 2, j = bj & 3;
    int pt = blockIdx.x * 16 + (threadIdx.x >> 4);
    int cg = threadIdx.x & 15;

    const float4* fj = reinterpret_cast<const float4*>(
        feats + ((size_t)bj*HW + pt)*64) + cg;
    float4 acc = *fj;
    float norm = 1.0f;
    int ns = nsl[j];
    for (int e = 0; e < 2; e++) {
        if (e < ns) {
            int p = slt[j][e], k = kvw[j][e];
            int s = b*6 + p;
            float scale = 0.1f * (float)counts[s] / 65536.0f;
            int mt = meta[(size_t)s*HW + pt];
            if (mt < 0) {
                int idx = mt & 0xFFFF;
                const float4* g = reinterpret_cast<const float4*>(
                    feats + ((size_t)(b*4 + k)*HW + idx)*64) + cg;
                float4 gv = *g;
                acc.x += scale * gv.x; acc.y += scale * gv.y;
                acc.z += scale * gv.z; acc.w += scale * gv.w;
            }
            norm += scale;
        }
    }
    float ox = acc.x / norm, oy = acc.y / norm;
    float oz = acc.z / norm, ow = acc.w / norm;

    int yy = pt >> 8, xx = pt & 255;
    unsigned short* op = fusedP +
        (((size_t)bj*NPAD + (yy+1))*NPAD + (xx+1))*64 + cg*4;
    ushort4 o = make_ushort4(f2bf(ox), f2bf(oy), f2bf(oz), f2bf(ow));
    *reinterpret_cast<ushort4*>(op) = o;
}

// ---------------------------------------------------------------------------
// 3x3 conv: block = 256 thr (4 waves), tile = 4 output rows x 64 px x 64 co.
// Stage 6 padded rows x 66 px into LDS via global_load_lds (16B), then 18
// shifted K=32 MFMA steps with ds_read_b128 A-frags; B-frags from L1.
// ---------------------------------------------------------------------------
template<int MODE>
__global__ __launch_bounds__(256) void conv_kernel(
    const unsigned short* __restrict__ in, const unsigned short* __restrict__ wT,
    const float* __restrict__ bias, void* __restrict__ outp)
{
    __shared__ unsigned short smem[6 * ROWSTRS];

    int n = blockIdx.z;
    int y0 = blockIdx.y * 4;       // first output row (unpadded)
    int X0 = blockIdx.x * 64;      // first output px (unpadded)
    int w  = threadIdx.x >> 6;     // wave id: output row y0+w
    int lane = threadIdx.x & 63;
    int m = lane & 15, q = lane >> 4;

    // Stage 6 padded rows [y0 .. y0+5] x padded px [X0 .. X0+65]
    for (int ri = w; ri < 6; ri += 4) {
        const char* g = (const char*)(in + ((size_t)(n*NPAD + y0 + ri)*NPAD + X0)*64);
        char* l = (char*)smem + ri*ROWSTR;
#pragma unroll
        for (int i = 0; i < 8; i++)
            __builtin_amdgcn_global_load_lds(
                (const __attribute__((address_space(1))) unsigned int*)(g + i*1024 + (size_t)lane*16),
                (__attribute__((address_space(3))) unsigned int*)(l + i*1024 + (size_t)lane*16),
                16, 0, 0);
        __builtin_amdgcn_global_load_lds(
            (const __attribute__((address_space(1))) unsigned int*)(g + 8192 + (size_t)lane*4),
            (__attribute__((address_space(3))) unsigned int*)(l + 8192 + (size_t)lane*4),
            4, 0, 0);
    }
    __syncthreads();

    f32x4 acc[4][4];
#pragma unroll
    for (int a = 0; a < 4; a++)
#pragma unroll
        for (int bq = 0; bq < 4; bq++)
            acc[a][bq] = (f32x4){0.f, 0.f, 0.f, 0.f};

#pragma unroll
    for (int h = 0; h < 2; h++) {
#pragma unroll
        for (int tap = 0; tap < 9; tap++) {
            int dy = tap/3, dx = tap%3;   // 0..2
            const unsigned short* lrow = smem + (w + dy)*ROWSTRS;
            bf16x8 av[4], bv[4];
#pragma unroll
            for (int Mt = 0; Mt < 4; Mt++)
                av[Mt] = *reinterpret_cast<const bf16x8*>(
                    lrow + (Mt*16 + m + dx)*64 + h*32 + q*8);
            const unsigned short* wp = wT + (size_t)(((h*9 + tap)*4 + q)*64)*8;
#pragma unroll
            for (int Nt = 0; Nt < 4; Nt++)
                bv[Nt] = *reinterpret_cast<const bf16x8*>(wp + (Nt*16 + m)*8);
#pragma unroll
            for (int Mt = 0; Mt < 4; Mt++)
#pragma unroll
                for (int Nt = 0; Nt < 4; Nt++)
                    acc[Mt][Nt] = __builtin_amdgcn_mfma_f32_16x16x32_bf16(
                        av[Mt], bv[Nt], acc[Mt][Nt], 0, 0, 0);
        }
    }

    // Epilogue. C/D: col(co) = lane&15, row(px) = (lane>>4)*4 + r
#pragma unroll
    for (int Nt = 0; Nt < 4; Nt++) {
        int co = Nt*16 + m;
        float bs = bias[co];
#pragma unroll
        for (int Mt = 0; Mt < 4; Mt++) {
#pragma unroll
            for (int r = 0; r < 4; r++) {
                float v = acc[Mt][Nt][r] + bs;
                int px = X0 + Mt*16 + q*4 + r;
                if (MODE == 1) {
                    v = 0.5f * v * (1.0f + erff(v * 0.70710678118654752f));
                    unsigned short* o = (unsigned short*)outp +
                        ((size_t)(n*NPAD + y0 + w + 1)*NPAD + (px + 1))*64 + co;
                    *o = f2bf(v);
                } else {
                    float* o = (float*)outp +
                        ((size_t)(n*256 + y0 + w)*256 + px)*64 + co;
                    *o = v;
                }
            }
        }
    }
}

extern "C" void kernel_launch(void* const* d_in, const int* in_sizes, int n_in,
                              void* d_out, int out_size, void* d_ws, size_t ws_size,
                              hipStream_t stream)
{
    const float* means = (const float*)d_in[0];
    const float* feats = (const float*)d_in[2];
    const float* intr  = (const float*)d_in[3];
    const float* extr  = (const float*)d_in[4];
    const float* w1    = (const float*)d_in[5];
    const float* b1    = (const float*)d_in[6];
    const float* w2    = (const float*)d_in[7];
    const float* b2    = (const float*)d_in[8];

    char* ws = (char*)d_ws;
    int*            counts = (int*)(ws + O_COUNTS);
    float*          w2c    = (float*)(ws + O_W2C);
    unsigned short* wT     = (unsigned short*)(ws + O_WT);
    int*            meta   = (int*)(ws + O_META);
    unsigned short* fusedP = (unsigned short*)(ws + O_FUSED);
    unsigned short* x1P    = (unsigned short*)(ws + O_X1);

    prep_kernel<<<dim3(96), dim3(256), 0, stream>>>(
        extr, w1, w2, w2c, wT, fusedP, x1P, counts);
    proj_kernel<<<dim3(256, 12), dim3(256), 0, stream>>>(
        means, intr, w2c, meta, counts);
    fuse_kernel<<<dim3(4096, 8), dim3(256), 0, stream>>>(
        feats, meta, counts, fusedP);
    conv_kernel<1><<<dim3(4, 64, 8), dim3(256), 0, stream>>>(
        fusedP, wT, b1, (void*)x1P);
    conv_kernel<2><<<dim3(4, 64, 8), dim3(256), 0, stream>>>(
        x1P, wT + 36864, b2, d_out);
}

// Round 3
// 416.853 us; speedup vs baseline: 1.6587x; 1.3376x over previous
//
#include <hip/hip_runtime.h>
#include <math.h>

// Problem constants
#define HW 65536          // 256*256
#define NPAD 258          // padded spatial dim

typedef short bf16x8 __attribute__((ext_vector_type(8)));
typedef float f32x4  __attribute__((ext_vector_type(4)));

// Workspace layout (bytes)
// counts: 12 slots spaced 32 ints (128 B) apart to avoid same-line atomic
// contention across XCDs.
#define O_COUNTS 0            // 12 * 32 ints = 1536 B
#define O_W2C    2048         // 8 * 16 floats = 512 B
#define O_WT     4096         // 2 convs * 36864 bf16 = 147456 B  [cv][h][tap][q][co][8ci]
#define O_META   151552       // 12 * 65536 ints = 3 MiB
#define O_FUSED  3297280      // 8*258*258*64 bf16 = 68,161,536 B
#define O_X1     71458816     // same size
// total ~= 139.6 MB

// Conv LDS tile: 6 padded rows x 66 px x 64ch bf16
#define ROWPX 66
#define ROWB  (ROWPX * 128)       // 8448 B per row
#define ROWSTR (ROWB + 16)        // +16 B pad between rows
#define ROWSTRS (ROWSTR / 2)      // stride in shorts (4232)

__device__ __forceinline__ unsigned short f2bf(float f) {
    unsigned int u = __float_as_uint(f);
    u += 0x7FFFu + ((u >> 16) & 1u);   // round-to-nearest-even
    return (unsigned short)(u >> 16);
}

// ---------------------------------------------------------------------------
// Prep: invert extrinsics, build bf16 weight fragment image [h][tap][q][co][8ci],
// zero padded-buffer borders, zero counts
// ---------------------------------------------------------------------------
__global__ __launch_bounds__(256) void prep_kernel(
    const float* __restrict__ extr, const float* __restrict__ w1,
    const float* __restrict__ w2, float* __restrict__ w2c,
    unsigned short* __restrict__ wT, unsigned short* __restrict__ fusedP,
    unsigned short* __restrict__ x1P, int* __restrict__ counts)
{
    int tid = blockIdx.x * blockDim.x + threadIdx.x;
    int nth = gridDim.x * blockDim.x;

    if (blockIdx.x == 0) {
        if (threadIdx.x < 8) {
            float a[4][8];
            const float* E = extr + threadIdx.x * 16;
            for (int r = 0; r < 4; r++)
                for (int c = 0; c < 4; c++) {
                    a[r][c] = E[r*4 + c];
                    a[r][4+c] = (r == c) ? 1.0f : 0.0f;
                }
            for (int col = 0; col < 4; col++) {
                int piv = col; float bm = fabsf(a[col][col]);
                for (int r = col+1; r < 4; r++) {
                    float v = fabsf(a[r][col]);
                    if (v > bm) { bm = v; piv = r; }
                }
                if (piv != col)
                    for (int c = 0; c < 8; c++) { float t = a[col][c]; a[col][c] = a[piv][c]; a[piv][c] = t; }
                float f = 1.0f / a[col][col];
                for (int c = 0; c < 8; c++) a[col][c] *= f;
                for (int r = 0; r < 4; r++) if (r != col) {
                    float f2 = a[r][col];
                    for (int c = 0; c < 8; c++) a[r][c] -= f2 * a[col][c];
                }
            }
            float* O = w2c + threadIdx.x * 16;
            for (int r = 0; r < 4; r++)
                for (int c = 0; c < 4; c++) O[r*4+c] = a[r][4+c];
        }
    }

    // Zero padded count slots (12 * 32 ints)
    for (int i = tid; i < 384; i += nth) counts[i] = 0;

    // Weight fragment image: 2 convs * [h2][tap9][q4][co64][j8]
    for (int e = tid; e < 73728; e += nth) {
        int t = e;
        int j  = t & 7;  t >>= 3;
        int co = t & 63; t >>= 6;
        int q  = t & 3;  t >>= 2;
        int tap = t % 9; t /= 9;
        int h  = t & 1;  int cv = t >> 1;
        int ci = h*32 + q*8 + j;
        int ky = tap / 3, kx = tap % 3;
        const float* wsrc = cv ? w2 : w1;
        float v = wsrc[((co*64 + ci)*3 + ky)*3 + kx];
        wT[cv*36864 + ((((h*9 + tap)*4 + q)*64 + co)*8 + j)] = f2bf(v);
    }

    // Zero borders of both padded buffers
    for (int u = tid; u < 2*8*1028*8; u += nth) {
        int t = u;
        int ch   = t & 7;    t >>= 3;
        int cell = t % 1028; t /= 1028;
        int n    = t & 7;    int buf = t >> 3;
        int y, x;
        if      (cell < 258) { y = 0;   x = cell; }
        else if (cell < 516) { y = 257; x = cell - 258; }
        else if (cell < 772) { y = cell - 516 + 1; x = 0; }
        else                 { y = cell - 772 + 1; x = 257; }
        unsigned short* p = (buf ? x1P : fusedP) +
            (((size_t)(n*NPAD + y)*NPAD + x)*64 + ch*8);
        *reinterpret_cast<uint4*>(p) = make_uint4(0u, 0u, 0u, 0u);
    }
}

// ---------------------------------------------------------------------------
// Projection: per (b, j->k) pair, compute mask|idx per point + valid counts.
// Two-level count reduction: ballot -> LDS -> ONE atomic per block, to
// 128B-spaced counter slots (kills cross-XCD same-line atomic serialization).
// ---------------------------------------------------------------------------
__global__ __launch_bounds__(256) void proj_kernel(
    const float* __restrict__ means, const float* __restrict__ intr,
    const float* __restrict__ w2c, int* __restrict__ meta,
    int* __restrict__ counts)
{
    const int jt[6] = {0,1,1,2,2,3};
    const int kt[6] = {1,0,2,1,3,2};
    int s = blockIdx.y;            // 0..11
    int b = s / 6, p = s % 6;
    int j = jt[p], k = kt[p];
    int i = blockIdx.x * 256 + threadIdx.x;

    __shared__ int bcnt;
    if (threadIdx.x == 0) bcnt = 0;
    __syncthreads();

    const float* mp = means + ((size_t)(b*4 + j)*HW + i)*3;
    float x = mp[0], y = mp[1], z = mp[2];
    const float* M = w2c + (b*4 + k)*16;
    const float* I = intr + (b*4 + k)*9;

    float cx = fmaf(M[2],  z, fmaf(M[1], y, M[0]*x)) + M[3];
    float cy = fmaf(M[6],  z, fmaf(M[5], y, M[4]*x)) + M[7];
    float cz = fmaf(M[10], z, fmaf(M[9], y, M[8]*x)) + M[11];

    bool vz = cz > 1e-8f;
    float zi = cz + 1e-8f;
    float sx = cx / zi, sy = cy / zi, sz = cz / zi;
    float nx = fmaf(I[2], sz, fmaf(I[1], sy, I[0]*sx));
    float ny = fmaf(I[5], sz, fmaf(I[4], sy, I[3]*sx));

    int px = (int)floorf(nx * 256.0f);
    int py = (int)floorf(ny * 256.0f);
    bool mask = (nx >= 0.0f) && (nx < 1.0f) && (ny >= 0.0f) && (ny < 1.0f) && vz;
    int pxc = min(max(px, 0), 255);
    int pyc = min(max(py, 0), 255);
    int idx = pyc*256 + pxc;
    meta[(size_t)s*HW + i] = idx | (mask ? (int)0x80000000 : 0);

    unsigned long long bal = __ballot(mask ? 1 : 0);
    if ((threadIdx.x & 63) == 0)
        atomicAdd(&bcnt, (int)__popcll(bal));
    __syncthreads();
    if (threadIdx.x == 0)
        atomicAdd(counts + s*32, bcnt);
}

// ---------------------------------------------------------------------------
// Fusion: acc = feats_j + sum_k scale_k * masked_gather(feats_k); /norm; bf16
// ---------------------------------------------------------------------------
__global__ __launch_bounds__(256) void fuse_kernel(
    const float* __restrict__ feats, const int* __restrict__ meta,
    const int* __restrict__ counts, unsigned short* __restrict__ fusedP)
{
    const int nsl[4]    = {1, 2, 2, 1};
    const int slt[4][2] = {{0,0},{1,2},{3,4},{5,5}};
    const int kvw[4][2] = {{1,1},{0,2},{1,3},{2,2}};

    int bj = blockIdx.y;           // n = b*4 + j
    int b = bj >> 2, j = bj & 3;
    int pt = blockIdx.x * 16 + (threadIdx.x >> 4);
    int cg = threadIdx.x & 15;

    const float4* fj = reinterpret_cast<const float4*>(
        feats + ((size_t)bj*HW + pt)*64) + cg;
    float4 acc = *fj;
    float norm = 1.0f;
    int ns = nsl[j];
    for (int e = 0; e < 2; e++) {
        if (e < ns) {
            int p = slt[j][e], k = kvw[j][e];
            int s = b*6 + p;
            float scale = 0.1f * (float)counts[s*32] / 65536.0f;
            int mt = meta[(size_t)s*HW + pt];
            if (mt < 0) {
                int idx = mt & 0xFFFF;
                const float4* g = reinterpret_cast<const float4*>(
                    feats + ((size_t)(b*4 + k)*HW + idx)*64) + cg;
                float4 gv = *g;
                acc.x += scale * gv.x; acc.y += scale * gv.y;
                acc.z += scale * gv.z; acc.w += scale * gv.w;
            }
            norm += scale;
        }
    }
    float ox = acc.x / norm, oy = acc.y / norm;
    float oz = acc.z / norm, ow = acc.w / norm;

    int yy = pt >> 8, xx = pt & 255;
    unsigned short* op = fusedP +
        (((size_t)bj*NPAD + (yy+1))*NPAD + (xx+1))*64 + cg*4;
    ushort4 o = make_ushort4(f2bf(ox), f2bf(oy), f2bf(oz), f2bf(ow));
    *reinterpret_cast<ushort4*>(op) = o;
}

// ---------------------------------------------------------------------------
// 3x3 conv: block = 256 thr (4 waves), tile = 4 output rows x 64 px x 64 co.
// Stage 6 padded rows x 66 px into LDS via global_load_lds (16B), then 18
// shifted K=32 MFMA steps with ds_read_b128 A-frags; B-frags from L1.
// ---------------------------------------------------------------------------
template<int MODE>
__global__ __launch_bounds__(256) void conv_kernel(
    const unsigned short* __restrict__ in, const unsigned short* __restrict__ wT,
    const float* __restrict__ bias, void* __restrict__ outp)
{
    __shared__ unsigned short smem[6 * ROWSTRS];

    int n = blockIdx.z;
    int y0 = blockIdx.y * 4;       // first output row (unpadded)
    int X0 = blockIdx.x * 64;      // first output px (unpadded)
    int w  = threadIdx.x >> 6;     // wave id: output row y0+w
    int lane = threadIdx.x & 63;
    int m = lane & 15, q = lane >> 4;

    // Stage 6 padded rows [y0 .. y0+5] x padded px [X0 .. X0+65]
    for (int ri = w; ri < 6; ri += 4) {
        const char* g = (const char*)(in + ((size_t)(n*NPAD + y0 + ri)*NPAD + X0)*64);
        char* l = (char*)smem + ri*ROWSTR;
#pragma unroll
        for (int i = 0; i < 8; i++)
            __builtin_amdgcn_global_load_lds(
                (const __attribute__((address_space(1))) unsigned int*)(g + i*1024 + (size_t)lane*16),
                (__attribute__((address_space(3))) unsigned int*)(l + i*1024 + (size_t)lane*16),
                16, 0, 0);
        __builtin_amdgcn_global_load_lds(
            (const __attribute__((address_space(1))) unsigned int*)(g + 8192 + (size_t)lane*4),
            (__attribute__((address_space(3))) unsigned int*)(l + 8192 + (size_t)lane*4),
            4, 0, 0);
    }
    __syncthreads();

    f32x4 acc[4][4];
#pragma unroll
    for (int a = 0; a < 4; a++)
#pragma unroll
        for (int bq = 0; bq < 4; bq++)
            acc[a][bq] = (f32x4){0.f, 0.f, 0.f, 0.f};

#pragma unroll
    for (int h = 0; h < 2; h++) {
#pragma unroll
        for (int tap = 0; tap < 9; tap++) {
            int dy = tap/3, dx = tap%3;   // 0..2
            const unsigned short* lrow = smem + (w + dy)*ROWSTRS;
            bf16x8 av[4], bv[4];
#pragma unroll
            for (int Mt = 0; Mt < 4; Mt++)
                av[Mt] = *reinterpret_cast<const bf16x8*>(
                    lrow + (Mt*16 + m + dx)*64 + h*32 + q*8);
            const unsigned short* wp = wT + (size_t)(((h*9 + tap)*4 + q)*64)*8;
#pragma unroll
            for (int Nt = 0; Nt < 4; Nt++)
                bv[Nt] = *reinterpret_cast<const bf16x8*>(wp + (Nt*16 + m)*8);
#pragma unroll
            for (int Mt = 0; Mt < 4; Mt++)
#pragma unroll
                for (int Nt = 0; Nt < 4; Nt++)
                    acc[Mt][Nt] = __builtin_amdgcn_mfma_f32_16x16x32_bf16(
                        av[Mt], bv[Nt], acc[Mt][Nt], 0, 0, 0);
        }
    }

    // Epilogue. C/D: col(co) = lane&15, row(px) = (lane>>4)*4 + r
#pragma unroll
    for (int Nt = 0; Nt < 4; Nt++) {
        int co = Nt*16 + m;
        float bs = bias[co];
#pragma unroll
        for (int Mt = 0; Mt < 4; Mt++) {
#pragma unroll
            for (int r = 0; r < 4; r++) {
                float v = acc[Mt][Nt][r] + bs;
                int px = X0 + Mt*16 + q*4 + r;
                if (MODE == 1) {
                    v = 0.5f * v * (1.0f + erff(v * 0.70710678118654752f));
                    unsigned short* o = (unsigned short*)outp +
                        ((size_t)(n*NPAD + y0 + w + 1)*NPAD + (px + 1))*64 + co;
                    *o = f2bf(v);
                } else {
                    float* o = (float*)outp +
                        ((size_t)(n*256 + y0 + w)*256 + px)*64 + co;
                    *o = v;
                }
            }
        }
    }
}

extern "C" void kernel_launch(void* const* d_in, const int* in_sizes, int n_in,
                              void* d_out, int out_size, void* d_ws, size_t ws_size,
                              hipStream_t stream)
{
    const float* means = (const float*)d_in[0];
    const float* feats = (const float*)d_in[2];
    const float* intr  = (const float*)d_in[3];
    const float* extr  = (const float*)d_in[4];
    const float* w1    = (const float*)d_in[5];
    const float* b1    = (const float*)d_in[6];
    const float* w2    = (const float*)d_in[7];
    const float* b2    = (const float*)d_in[8];

    char* ws = (char*)d_ws;
    int*            counts = (int*)(ws + O_COUNTS);
    float*          w2c    = (float*)(ws + O_W2C);
    unsigned short* wT     = (unsigned short*)(ws + O_WT);
    int*            meta   = (int*)(ws + O_META);
    unsigned short* fusedP = (unsigned short*)(ws + O_FUSED);
    unsigned short* x1P    = (unsigned short*)(ws + O_X1);

    prep_kernel<<<dim3(96), dim3(256), 0, stream>>>(
        extr, w1, w2, w2c, wT, fusedP, x1P, counts);
    proj_kernel<<<dim3(256, 12), dim3(256), 0, stream>>>(
        means, intr, w2c, meta, counts);
    fuse_kernel<<<dim3(4096, 8), dim3(256), 0, stream>>>(
        feats, meta, counts, fusedP);
    conv_kernel<1><<<dim3(4, 64, 8), dim3(256), 0, stream>>>(
        fusedP, wT, b1, (void*)x1P);
    conv_kernel<2><<<dim3(4, 64, 8), dim3(256), 0, stream>>>(
        x1P, wT + 36864, b2, d_out);
}